// Round 6
// baseline (35.856 us; speedup 1.0000x reference)
//
#include <hip/hip_runtime.h>
#include <stdint.h>

#define TLEN    96512
#define NBATCH  32
#define KOUT    256
#define SHIFT   160
#define NFRAMES 601
#define FT      32            // frames per block
#define NTILES  19            // 19*32 = 608 >= 601
#define NKS     16            // K-steps of 16 over folded K=256
#define EPSF    1e-7f

typedef _Float16 f16;
typedef _Float16 half8 __attribute__((ext_vector_type(8)));
typedef float f32x16 __attribute__((ext_vector_type(16)));

// E/O stream span per f-tile
#define SPAN       ((FT - 1) * SHIFT + 256)   // 5216
#define UNITS      (SPAN / 8)                 // 652 16B-units per plane
#define PLANE_B    (UNITS * 16)               // 10432 B
#define LDS_RED    (4 * PLANE_B)              // 41728
#define LDS_STAT   (LDS_RED + 2048)           // 8w x 32 float2
#define LDS_TOTAL  (LDS_STAT + 256)           // 44032 -> 2 blocks/CU (LDS), 4 waves/SIMD

// ============================================================================
// W' workspace: radix-2 folded, f16 hi/lo, MFMA-fragment-ready. 512 KB.
// chunk c = ((par*4 + J)*16 + ks)*4 + ri*2 + hl   (512 chunks x 1KB)
// within chunk: lane (l31,lhi) at halves offset (l31*2+lhi)*8
// A-value = W[k][n], k = 2*(J*32+l31)+par, n = ks*16 + lhi*8   (n < 256)
// ============================================================================
__global__ __launch_bounds__(256) void split_w_kernel(
    const float* __restrict__ Wr, const float* __restrict__ Wi,
    f16* __restrict__ wsW)
{
    int id = blockIdx.x * 256 + threadIdx.x;   // 16384 threads
    int n8 = id & 31;                          // 8-float column group
    int k  = (id >> 5) & 255;
    int ri = (id >> 13) & 1;
    // coalesced read: lanes sweep n8 within a row (1KB contiguous per 32 lanes)
    const float* src = (ri ? Wi : Wr) + k * 512 + n8 * 8;
    f16 h[8], l[8];
    #pragma unroll
    for (int j = 0; j < 8; ++j) {
        float v = src[j];
        h[j] = (f16)v;
        l[j] = (f16)(v - (float)h[j]);
    }
    int par = k & 1, kk = k >> 1;
    int l31 = kk & 31, J = kk >> 5;
    int ks  = n8 >> 1, lhi = n8 & 1;
    int c0  = ((par * 4 + J) * 16 + ks) * 4 + ri * 2;      // hl=0
    size_t off = (size_t)(l31 * 2 + lhi) * 8;
    *(half8*)(wsW + (size_t)(c0 + 0) * 512 + off) = *(half8*)h;
    *(half8*)(wsW + (size_t)(c0 + 1) * 512 + off) = *(half8*)l;
}

// ---------------- K-loop helpers ----------------
__device__ __forceinline__ void load_a(half8 (&a)[2][2],
    const f16* __restrict__ wsW, int cbase, int laneoff, int ks)
{
    #pragma unroll
    for (int ri = 0; ri < 2; ++ri)
      #pragma unroll
      for (int hl = 0; hl < 2; ++hl) {
          int c = cbase + ks * 4 + ri * 2 + hl;
          a[ri][hl] = *(const half8*)(wsW + (size_t)c * 512 + laneoff);
      }
}

__device__ __forceinline__ void load_b(half8 (&bb)[2],
    const char* smem, int par, int ubase, int ks)
{
    int u  = ubase + ks * 2;
    int up = u ^ ((u >> 3) & 3);
    #pragma unroll
    for (int hl = 0; hl < 2; ++hl)
        bb[hl] = *(const half8*)(smem + (par * 2 + hl) * PLANE_B + up * 16);
}

// ============================================================================
// Main kernel: 512 thr = 8 waves; wave = 32 k-rows x 32 f-cols (skinny tile,
// ~100 regs -> 4 waves/SIMD). All 8 waves share the same 32 f-cols; k is
// partitioned by (par, J). K-loop barrier-free.
// ============================================================================
__global__ __launch_bounds__(512, 4) void dft_mfma_kernel(
    const f16* __restrict__ wsW, const float* __restrict__ x,
    float* __restrict__ out)
{
    __shared__ uint4 smem4[LDS_TOTAL / 16];
    char* smem = (char*)smem4;

    const int tid  = threadIdx.x;
    const int lane = tid & 63;
    const int w    = tid >> 6;      // 0..7
    const int l31  = lane & 31;
    const int lhi  = lane >> 5;
    const int b    = blockIdx.y;
    const int f0   = blockIdx.x * FT;
    const int par  = w & 1;         // 0 -> E planes, 1 -> O planes
    const int J    = w >> 1;        // 0..3
    const int cbase   = (par * 4 + J) * 64;        // chunk base for this wave
    const int laneoff = (l31 * 2 + lhi) * 8;       // halves
    const int ubase   = l31 * 20 + lhi;            // B unit base

    // ---- stage E/O hi/lo planes (one-time) ----
    {
        const float* __restrict__ xb = x + (size_t)b * TLEN;
        const int t0 = f0 * SHIFT;
        for (int u = tid; u < UNITS; u += 512) {
            int t = t0 + u * 8;
            float va[8], vb[8];
            if (t + 264 <= TLEN) {
                float4 p0 = *(const float4*)(xb + t);
                float4 p1 = *(const float4*)(xb + t + 4);
                float4 q0 = *(const float4*)(xb + t + 256);
                float4 q1 = *(const float4*)(xb + t + 260);
                va[0]=p0.x; va[1]=p0.y; va[2]=p0.z; va[3]=p0.w;
                va[4]=p1.x; va[5]=p1.y; va[6]=p1.z; va[7]=p1.w;
                vb[0]=q0.x; vb[1]=q0.y; vb[2]=q0.z; vb[3]=q0.w;
                vb[4]=q1.x; vb[5]=q1.y; vb[6]=q1.z; vb[7]=q1.w;
            } else {
                #pragma unroll
                for (int j = 0; j < 8; ++j) {
                    int ta = t + j, tb = t + 256 + j;
                    va[j] = (ta < TLEN) ? xb[ta] : 0.f;
                    vb[j] = (tb < TLEN) ? xb[tb] : 0.f;
                }
            }
            f16 eh[8], el[8], oh[8], ol[8];
            #pragma unroll
            for (int j = 0; j < 8; ++j) {
                float E = va[j] + vb[j], O = va[j] - vb[j];
                eh[j] = (f16)E; el[j] = (f16)(E - (float)eh[j]);
                oh[j] = (f16)O; ol[j] = (f16)(O - (float)oh[j]);
            }
            int up = u ^ ((u >> 3) & 3);
            *(half8*)(smem + 0 * PLANE_B + up * 16) = *(half8*)eh;
            *(half8*)(smem + 1 * PLANE_B + up * 16) = *(half8*)el;
            *(half8*)(smem + 2 * PLANE_B + up * 16) = *(half8*)oh;
            *(half8*)(smem + 3 * PLANE_B + up * 16) = *(half8*)ol;
        }
    }
    __syncthreads();

    f32x16 acc[2] = {};    // [ri]

    #pragma unroll 4
    for (int ks = 0; ks < NKS; ++ks) {
        half8 a[2][2], bb[2];
        load_a(a, wsW, cbase, laneoff, ks);
        load_b(bb, smem, par, ubase, ks);

        __builtin_amdgcn_s_setprio(1);
        #pragma unroll
        for (int ri = 0; ri < 2; ++ri) {
            acc[ri] = __builtin_amdgcn_mfma_f32_32x32x16_f16(
                a[ri][0], bb[0], acc[ri], 0, 0, 0);   // hh
            acc[ri] = __builtin_amdgcn_mfma_f32_32x32x16_f16(
                a[ri][0], bb[1], acc[ri], 0, 0, 0);   // h*l
            acc[ri] = __builtin_amdgcn_mfma_f32_32x32x16_f16(
                a[ri][1], bb[0], acc[ri], 0, 0, 0);   // l*h
        }
        __builtin_amdgcn_s_setprio(0);
    }

    // ---- epilogue: log-magnitude + per-(b,f) mean/std over k ----
    const float C = 0.15051499783199057f;    // 0.5*log10(2)
    float lg[16];
    float s1 = 0.f, s2 = 0.f;
    #pragma unroll
    for (int r = 0; r < 16; ++r) {
        float re = acc[0][r], im = acc[1][r];
        float lv = C * __log2f(re * re + im * im + EPSF);
        lg[r] = lv;
        s1 += lv;
        s2 += lv * lv;
    }
    // fold lanes l <-> l+32 (same f col, different k rows)
    s1 += __shfl_xor(s1, 32);
    s2 += __shfl_xor(s2, 32);

    float2* red = (float2*)(smem + LDS_RED);
    if (lane < 32)
        red[w * 32 + l31] = make_float2(s1, s2);
    __syncthreads();
    float* stat = (float*)(smem + LDS_STAT);    // mean[32], rstd[32]
    if (tid < 32) {
        float S1 = 0.f, S2 = 0.f;
        #pragma unroll
        for (int ww = 0; ww < 8; ++ww) {
            float2 p = red[ww * 32 + tid];
            S1 += p.x; S2 += p.y;
        }
        float mean = S1 * (1.f / 256.f);
        float var  = fmaxf(S2 * (1.f / 256.f) - mean * mean, 0.f);
        stat[tid]      = mean;
        stat[32 + tid] = 1.f / (__builtin_sqrtf(var) + EPSF);
    }
    __syncthreads();

    const int f = f0 + l31;
    if (f < NFRAMES) {
        float mean = stat[l31], rstd = stat[32 + l31];
        #pragma unroll
        for (int r = 0; r < 16; ++r) {
            int k = 2 * (J * 32 + (r & 3) + 8 * (r >> 2) + 4 * lhi) + par;
            out[((size_t)b * KOUT + k) * NFRAMES + f] = (lg[r] - mean) * rstd;
        }
    }
}

extern "C" void kernel_launch(void* const* d_in, const int* in_sizes, int n_in,
                              void* d_out, int out_size, void* d_ws, size_t ws_size,
                              hipStream_t stream) {
    const float* x  = (const float*)d_in[0];
    const float* Wr = (const float*)d_in[1];
    const float* Wi = (const float*)d_in[2];
    float* out = (float*)d_out;

    f16* wsW = (f16*)d_ws;   // 512 KB

    split_w_kernel<<<64, 256, 0, stream>>>(Wr, Wi, wsW);

    dim3 grid(NTILES, NBATCH);   // 19 x 32 = 608 blocks, 2/CU co-resident 512
    dft_mfma_kernel<<<grid, 512, 0, stream>>>(wsW, x, out);
}

// Round 7
// 35.523 us; speedup vs baseline: 1.0094x; 1.0094x over previous
//
#include <hip/hip_runtime.h>
#include <stdint.h>

#define TLEN    96512
#define NBATCH  32
#define KOUT    256
#define SHIFT   160
#define NFRAMES 601
#define FT      76            // frames per block (76*8 = 608 >= 601)
#define NTILES  8
#define NKS     16            // K-steps of 16 over folded K=256
#define EPSF    1e-7f

typedef _Float16 f16;
typedef _Float16 half8 __attribute__((ext_vector_type(8)));
typedef float f32x16 __attribute__((ext_vector_type(16)));

// E/O stream span per f-tile: (FT-1)*160 + 256 samples
#define SPAN       ((FT - 1) * SHIFT + 256)   // 12256
#define UNITS      (SPAN / 8)                 // 1532 16B-units (real data)
#define PLANE_B    24576                      // plane stride (padded)
#define LDS_RED    104768                     // 4*PLANE_B + overflow slack (cols >= FT)
#define LDS_STAT   (LDS_RED + 6144)           // 8w x 3nf x 32 float2
#define LDS_TOTAL  (LDS_STAT + 768)           // 111680 -> 1 block/CU
// epilogue reuses [0, 98304) as 8 per-wave 32x96 f32 transpose patches

// ============================================================================
// W' workspace: radix-2 folded, f16 hi/lo, MFMA-fragment-ready. 512 KB.
// chunk c = ((par*4 + J)*16 + ks)*4 + ri*2 + hl   (512 chunks x 1KB)
// within chunk: lane (l31,lhi) at halves offset (l31*2+lhi)*8
// A-value = W[k][n], k = 2*(J*32+l31)+par, n = ks*16 + lhi*8   (n < 256)
// ============================================================================
__global__ __launch_bounds__(256) void split_w_kernel(
    const float* __restrict__ Wr, const float* __restrict__ Wi,
    f16* __restrict__ wsW)
{
    int id = blockIdx.x * 256 + threadIdx.x;   // 16384 threads
    int n8 = id & 31;                          // 8-float column group (n<256)
    int k  = (id >> 5) & 255;
    int ri = (id >> 13) & 1;
    // coalesced read: 32 lanes sweep a row's first 1KB contiguously
    const float* src = (ri ? Wi : Wr) + k * 512 + n8 * 8;
    f16 h[8], l[8];
    #pragma unroll
    for (int j = 0; j < 8; ++j) {
        float v = src[j];
        h[j] = (f16)v;
        l[j] = (f16)(v - (float)h[j]);
    }
    int par = k & 1, kk = k >> 1;
    int l31 = kk & 31, J = kk >> 5;
    int ks  = n8 >> 1, lhi = n8 & 1;
    int c0  = ((par * 4 + J) * 16 + ks) * 4 + ri * 2;      // hl=0
    size_t off = (size_t)(l31 * 2 + lhi) * 8;
    *(half8*)(wsW + (size_t)(c0 + 0) * 512 + off) = *(half8*)h;
    *(half8*)(wsW + (size_t)(c0 + 1) * 512 + off) = *(half8*)l;
}

// ---------------- K-loop helpers (all indices compile-time after unroll) ----
__device__ __forceinline__ void load_a(half8 (&a)[2][2],
    const f16* __restrict__ wsW, int par, int J, int laneoff, int ks)
{
    #pragma unroll
    for (int ri = 0; ri < 2; ++ri)
      #pragma unroll
      for (int hl = 0; hl < 2; ++hl) {
          int c = ((par * 4 + J) * 16 + ks) * 4 + ri * 2 + hl;
          a[ri][hl] = *(const half8*)(wsW + (size_t)c * 512 + laneoff);
      }
}

__device__ __forceinline__ void load_b(half8 (&bb)[3][2],
    const char* smem, int par, int l31, int lhi, int ks)
{
    #pragma unroll
    for (int nf = 0; nf < 3; ++nf)
      #pragma unroll
      for (int hl = 0; hl < 2; ++hl) {
          int u  = (nf * 32 + l31) * 20 + ks * 2 + lhi;
          int up = u ^ ((u >> 3) & 7);
          bb[nf][hl] = *(const half8*)(smem + (par * 2 + hl) * PLANE_B + up * 16);
      }
}

__device__ __forceinline__ void do_mfma(f32x16 (&acc)[3][2],
    const half8 (&a)[2][2], const half8 (&bb)[3][2])
{
    __builtin_amdgcn_s_setprio(1);
    #pragma unroll
    for (int nf = 0; nf < 3; ++nf)
      #pragma unroll
      for (int ri = 0; ri < 2; ++ri) {
          acc[nf][ri] = __builtin_amdgcn_mfma_f32_32x32x16_f16(
              a[ri][0], bb[nf][0], acc[nf][ri], 0, 0, 0);   // hh
          acc[nf][ri] = __builtin_amdgcn_mfma_f32_32x32x16_f16(
              a[ri][0], bb[nf][1], acc[nf][ri], 0, 0, 0);   // h*l
          acc[nf][ri] = __builtin_amdgcn_mfma_f32_32x32x16_f16(
              a[ri][1], bb[nf][0], acc[nf][ri], 0, 0, 0);   // l*h
      }
    __builtin_amdgcn_s_setprio(0);
}

// ============================================================================
// Main kernel: 512 thr = 8 waves; wave = 32 k-rows (one parity) x 96 f-cols.
// Grid 8x32 = 256 blocks = exactly 1 per CU. A from global (W', reg-dbuf).
// B from LDS (read-only after stage). K-loop barrier-free. Coalesced
// transpose-store epilogue (256B contiguous wave runs).
// ============================================================================
__global__ __launch_bounds__(512, 2) void dft_mfma_kernel(
    const f16* __restrict__ wsW, const float* __restrict__ x,
    float* __restrict__ out)
{
    __shared__ uint4 smem4[LDS_TOTAL / 16];
    char* smem = (char*)smem4;

    const int tid  = threadIdx.x;
    const int lane = tid & 63;
    const int w    = tid >> 6;      // 0..7
    const int l31  = lane & 31;
    const int lhi  = lane >> 5;
    const int b    = blockIdx.y;
    const int f0   = blockIdx.x * FT;
    const int par  = w & 1;         // 0 -> E planes, 1 -> O planes
    const int J    = w >> 1;        // 0..3
    const int laneoff = (l31 * 2 + lhi) * 8;   // halves

    // ---- prefetch A(ks=0) early: global loads overlap the staging loop ----
    half8 a0[2][2], a1[2][2], b0[3][2], b1[3][2];
    load_a(a0, wsW, par, J, laneoff, 0);

    // ---- stage E/O hi/lo planes (one-time) ----
    {
        const float* __restrict__ xb = x + (size_t)b * TLEN;
        const int t0 = f0 * SHIFT;
        for (int u = tid; u < UNITS; u += 512) {
            int t = t0 + u * 8;
            float va[8], vb[8];
            if (t + 264 <= TLEN) {
                float4 p0 = *(const float4*)(xb + t);
                float4 p1 = *(const float4*)(xb + t + 4);
                float4 q0 = *(const float4*)(xb + t + 256);
                float4 q1 = *(const float4*)(xb + t + 260);
                va[0]=p0.x; va[1]=p0.y; va[2]=p0.z; va[3]=p0.w;
                va[4]=p1.x; va[5]=p1.y; va[6]=p1.z; va[7]=p1.w;
                vb[0]=q0.x; vb[1]=q0.y; vb[2]=q0.z; vb[3]=q0.w;
                vb[4]=q1.x; vb[5]=q1.y; vb[6]=q1.z; vb[7]=q1.w;
            } else {
                #pragma unroll
                for (int j = 0; j < 8; ++j) {
                    int ta = t + j, tb = t + 256 + j;
                    va[j] = (ta < TLEN) ? xb[ta] : 0.f;
                    vb[j] = (tb < TLEN) ? xb[tb] : 0.f;
                }
            }
            f16 eh[8], el[8], oh[8], ol[8];
            #pragma unroll
            for (int j = 0; j < 8; ++j) {
                float E = va[j] + vb[j], O = va[j] - vb[j];
                eh[j] = (f16)E; el[j] = (f16)(E - (float)eh[j]);
                oh[j] = (f16)O; ol[j] = (f16)(O - (float)oh[j]);
            }
            int up = u ^ ((u >> 3) & 7);
            *(half8*)(smem + 0 * PLANE_B + up * 16) = *(half8*)eh;
            *(half8*)(smem + 1 * PLANE_B + up * 16) = *(half8*)el;
            *(half8*)(smem + 2 * PLANE_B + up * 16) = *(half8*)oh;
            *(half8*)(smem + 3 * PLANE_B + up * 16) = *(half8*)ol;
        }
    }
    __syncthreads();    // the ONLY barrier before the epilogue

    f32x16 acc[3][2] = {};    // [nf][ri]
    load_b(b0, smem, par, l31, lhi, 0);

    #pragma unroll
    for (int ks2 = 0; ks2 < NKS; ks2 += 2) {
        load_a(a1, wsW, par, J, laneoff, ks2 + 1);
        load_b(b1, smem, par, l31, lhi, ks2 + 1);
        do_mfma(acc, a0, b0);
        int k2 = (ks2 + 2 < NKS) ? ks2 + 2 : NKS - 1;   // tail: redundant reload
        load_a(a0, wsW, par, J, laneoff, k2);
        load_b(b0, smem, par, l31, lhi, k2);
        do_mfma(acc, a1, b1);
    }

    // ---- epilogue: log-magnitude + per-(b,f) mean/std over k ----
    const float C = 0.15051499783199057f;    // 0.5*log10(2)
    float lg[3][16];
    float s1[3] = {0.f, 0.f, 0.f}, s2[3] = {0.f, 0.f, 0.f};
    #pragma unroll
    for (int nf = 0; nf < 3; ++nf)
      #pragma unroll
      for (int r = 0; r < 16; ++r) {
          float re = acc[nf][0][r], im = acc[nf][1][r];
          float lv = C * __log2f(re * re + im * im + EPSF);
          lg[nf][r] = lv;
          s1[nf] += lv;
          s2[nf] += lv * lv;
      }
    #pragma unroll
    for (int nf = 0; nf < 3; ++nf) {        // fold lanes l <-> l+32 (same f col)
        s1[nf] += __shfl_xor(s1[nf], 32);
        s2[nf] += __shfl_xor(s2[nf], 32);
    }
    float2* red = (float2*)(smem + LDS_RED);
    if (lane < 32) {
        #pragma unroll
        for (int nf = 0; nf < 3; ++nf)
            red[(w * 3 + nf) * 32 + l31] = make_float2(s1[nf], s2[nf]);
    }
    __syncthreads();
    float* stat = (float*)(smem + LDS_STAT);    // mean[96], rstd[96]
    if (tid < 96) {
        float S1 = 0.f, S2 = 0.f;
        int nf = tid >> 5, c = tid & 31;
        #pragma unroll
        for (int ww = 0; ww < 8; ++ww) {
            float2 p = red[(ww * 3 + nf) * 32 + c];
            S1 += p.x; S2 += p.y;
        }
        float mean = S1 * (1.f / 256.f);
        float var  = fmaxf(S2 * (1.f / 256.f) - mean * mean, 0.f);
        stat[tid]      = mean;
        stat[96 + tid] = 1.f / (__builtin_sqrtf(var) + EPSF);
    }
    __syncthreads();   // stats ready; all waves past K-loop -> planes reusable

    // ---- coalesced transpose-store: per-wave 32x96 patch in dead plane LDS ----
    float* patch = (float*)smem + w * (32 * 96);   // 12 KB per wave, [0,98304)
    #pragma unroll
    for (int nf = 0; nf < 3; ++nf) {
        int fl = nf * 32 + l31;
        float mean = stat[fl], rstd = stat[96 + fl];
        #pragma unroll
        for (int r = 0; r < 16; ++r) {
            int kloc = (r & 3) + 8 * (r >> 2) + 4 * lhi;
            patch[kloc * 96 + fl] = (lg[nf][r] - mean) * rstd;
        }
    }
    // within-wave RAW on LDS; compiler inserts the lgkm wait. No cross-wave use.
    #pragma unroll 8
    for (int kloc = 0; kloc < 32; ++kloc) {
        int kg = 2 * (J * 32 + kloc) + par;
        float* dst = out + ((size_t)b * KOUT + kg) * NFRAMES + f0;
        float v0 = patch[kloc * 96 + lane];
        if (f0 + lane < NFRAMES)
            dst[lane] = v0;                       // 64 contiguous dwords
        if (lane < FT - 64 && f0 + 64 + lane < NFRAMES) {
            float v1 = patch[kloc * 96 + 64 + lane];
            dst[64 + lane] = v1;                  // remaining 12 dwords
        }
    }
}

extern "C" void kernel_launch(void* const* d_in, const int* in_sizes, int n_in,
                              void* d_out, int out_size, void* d_ws, size_t ws_size,
                              hipStream_t stream) {
    const float* x  = (const float*)d_in[0];
    const float* Wr = (const float*)d_in[1];
    const float* Wi = (const float*)d_in[2];
    float* out = (float*)d_out;

    f16* wsW = (f16*)d_ws;   // 512 KB

    split_w_kernel<<<64, 256, 0, stream>>>(Wr, Wi, wsW);

    dim3 grid(NTILES, NBATCH);   // 8 x 32 = 256 blocks, 1 per CU
    dft_mfma_kernel<<<grid, 512, 0, stream>>>(wsW, x, out);
}